// Round 1
// baseline (699.511 us; speedup 1.0000x reference)
//
#include <hip/hip_runtime.h>
#include <hip/hip_bf16.h>

// Problem constants (from reference): B,T,M,D,DOUT = 2,10000,100000,128,128
#define BB    2
#define TT    10000
#define MM    100000
#define DD    128
#define DOUTN 128
#define NROWS (BB * TT * 2)     // 40000 rows of X / y / out
#define NTILES (NROWS / 16)     // 2500 MFMA row-tiles (exact)
#define WPITCH 136              // LDS pitch in shorts: 272 B/row -> 2-way-only bank aliasing
#define CSR_NB 256              // <= 256 CUs -> co-residency unconditional (>=1 block/CU)

typedef float  f32x4  __attribute__((ext_vector_type(4)));
typedef short  bf16x8 __attribute__((ext_vector_type(8)));

static __device__ __forceinline__ short f2bf(float f) {
    union { float f; unsigned u; } v; v.f = f;
    unsigned r = v.u + 0x7fffu + ((v.u >> 16) & 1u);   // RNE
    return (short)(r >> 16);
}

// ---------------------------------------------------------------------------
// GEMM: y = X * W^T (no bias). Block stages W->bf16 in LDS once; each wave
// computes one 16-row x 128-col tile. 625 blocks x 4 waves = 2500 tiles exact.
// (Unchanged: already at its ~40 MB HBM-traffic floor.)
// ---------------------------------------------------------------------------
__global__ __launch_bounds__(256)
void gemm_y_kernel(const float* __restrict__ X, const float* __restrict__ W,
                   float* __restrict__ y) {
    __shared__ __align__(16) short Wb[DOUTN * WPITCH];   // 34.8 KB

    const int tid = threadIdx.x;
    {
        const int n  = tid >> 1;            // output col 0..127
        const int kh = (tid & 1) * 64;      // k half
        const float* wp = W + n * DD + kh;
        short* dst = &Wb[n * WPITCH + kh];
#pragma unroll
        for (int e = 0; e < 8; ++e) {
            float4 a = *(const float4*)(wp + e * 8);
            float4 b = *(const float4*)(wp + e * 8 + 4);
            bf16x8 t;
            t[0] = f2bf(a.x); t[1] = f2bf(a.y); t[2] = f2bf(a.z); t[3] = f2bf(a.w);
            t[4] = f2bf(b.x); t[5] = f2bf(b.y); t[6] = f2bf(b.z); t[7] = f2bf(b.w);
            *(bf16x8*)(dst + e * 8) = t;
        }
    }
    __syncthreads();

    const int lane = tid & 63;
    const int wid  = tid >> 6;
    const int l15  = lane & 15;
    const int q    = lane >> 4;             // 0..3
    const int tile = blockIdx.x * 4 + wid;  // 0..2499, always valid

    bf16x8 bfrag[8][4];
#pragma unroll
    for (int ot = 0; ot < 8; ++ot)
#pragma unroll
        for (int s = 0; s < 4; ++s)
            bfrag[ot][s] = *(const bf16x8*)&Wb[(ot * 16 + l15) * WPITCH + s * 32 + q * 8];

    const float* xp = X + (size_t)(tile * 16 + l15) * DD + q * 8;
    bf16x8 afrag[4];
#pragma unroll
    for (int s = 0; s < 4; ++s) {
        float4 a0 = *(const float4*)(xp + s * 32);
        float4 a1 = *(const float4*)(xp + s * 32 + 4);
        bf16x8 t;
        t[0] = f2bf(a0.x); t[1] = f2bf(a0.y); t[2] = f2bf(a0.z); t[3] = f2bf(a0.w);
        t[4] = f2bf(a1.x); t[5] = f2bf(a1.y); t[6] = f2bf(a1.z); t[7] = f2bf(a1.w);
        afrag[s] = t;
    }

    f32x4 acc[8];
#pragma unroll
    for (int ot = 0; ot < 8; ++ot) acc[ot] = (f32x4){0.f, 0.f, 0.f, 0.f};
#pragma unroll
    for (int s = 0; s < 4; ++s)
#pragma unroll
        for (int ot = 0; ot < 8; ++ot)
            acc[ot] = __builtin_amdgcn_mfma_f32_16x16x32_bf16(afrag[s], bfrag[ot][s], acc[ot], 0, 0, 0);

#pragma unroll
    for (int ot = 0; ot < 8; ++ot) {
        const int col = ot * 16 + l15;
#pragma unroll
        for (int r = 0; r < 4; ++r) {
            const int row = tile * 16 + q * 4 + r;
            y[(size_t)row * DOUTN + col] = acc[ot][r];
        }
    }
}

// ---------------------------------------------------------------------------
// Fused CSR build: hist -> grid-barrier -> scan (block 0) -> grid-barrier -> fill.
// Hand-rolled grid barrier: 256 blocks on 256 CUs is always fully resident
// (>=1 block/CU regardless of VGPR/LDS), so the spin cannot deadlock.
// Barrier counters live in ws and are zeroed by the same memset as `cur`.
// ---------------------------------------------------------------------------
static __device__ __forceinline__ void grid_bar(int* c, int nb) {
    __syncthreads();
    if (threadIdx.x == 0) {
        __threadfence();                     // release: prior stores/atomics visible device-wide
        atomicAdd(c, 1);                     // device-scope by default
        while (__hip_atomic_load(c, __ATOMIC_ACQUIRE, __HIP_MEMORY_SCOPE_AGENT) < nb) {
            __builtin_amdgcn_s_sleep(8);
        }
    }
    __syncthreads();
}

__global__ __launch_bounds__(256, 2)
void csr_kernel(const int* __restrict__ edge, int* __restrict__ cur,
                int* __restrict__ bucket, int* __restrict__ bar) {
    const int tid = threadIdx.x;

    // phase 1: histogram of destinations (edge[0][m])
    for (int m = blockIdx.x * 256 + tid; m < MM; m += 256 * CSR_NB)
        atomicAdd(&cur[edge[m]], 1);

    grid_bar(&bar[0], CSR_NB);

    // phase 2: exclusive prefix scan of cur[0..TT) by block 0 (256 thr x 40 chunks)
    if (blockIdx.x == 0) {
        __shared__ int sh[256];
        int vals[40];
        int sum = 0;
        const int base_i = tid * 40;
#pragma unroll
        for (int j = 0; j < 40; ++j) {
            const int i = base_i + j;
            const int v = (i < TT)
                ? __hip_atomic_load(&cur[i], __ATOMIC_RELAXED, __HIP_MEMORY_SCOPE_AGENT) : 0;
            vals[j] = v; sum += v;
        }
        sh[tid] = sum;
        __syncthreads();
        for (int off = 1; off < 256; off <<= 1) {
            const int v = (tid >= off) ? sh[tid - off] : 0;
            __syncthreads();
            sh[tid] += v;
            __syncthreads();
        }
        int run = (tid == 0) ? 0 : sh[tid - 1];
#pragma unroll
        for (int j = 0; j < 40; ++j) {
            const int i = base_i + j;
            if (i < TT) {
                __hip_atomic_store(&cur[i], run, __ATOMIC_RELAXED, __HIP_MEMORY_SCOPE_AGENT);
                run += vals[j];
            }
        }
    }

    grid_bar(&bar[1], CSR_NB);

    // phase 3: fill buckets; afterwards cur[t] == end offset of bucket t
    for (int m = blockIdx.x * 256 + tid; m < MM; m += 256 * CSR_NB) {
        const int p = atomicAdd(&cur[edge[m]], 1);
        bucket[p] = m;
    }
}

// ---------------------------------------------------------------------------
// Gather: one WAVE per node t handles all 4 (b,c) output rows.
//   out[(b,t,c),:] = y[(b,t,c),:] + bias + sum_{m: in_m=t} Am[b,m]*y[(b,out_m,c),:]
// Edge loop unrolled x2: 8 independent row-loads in flight per wait instead of
// 4, halving exposed L2/L3 latency per edge.
// ---------------------------------------------------------------------------
__global__ __launch_bounds__(256)
void gather_kernel(const float* __restrict__ y, const int* __restrict__ edge,
                   const float* __restrict__ Am, const int* __restrict__ cur_end,
                   const int* __restrict__ bucket, const float* __restrict__ bias,
                   float* __restrict__ out) {
    const int lane = threadIdx.x & 63;
    const int t    = blockIdx.x * 4 + (threadIdx.x >> 6);   // 2500*4 = 10000 exact

    const int end   = cur_end[t];
    const int start = (t == 0) ? 0 : cur_end[t - 1];

    // accumulators: a[b][c] as float2 per lane; init with own row of y
    const float* yb0 = y + (size_t)t * 256;            // (b0,t,c0) row; c1 at +128
    const float* yb1 = y + (size_t)(TT + t) * 256;     // (b1,t,c0) row; c1 at +128
    float2 a00 = ((const float2*)yb0)[lane];
    float2 a01 = ((const float2*)(yb0 + 128))[lane];
    float2 a10 = ((const float2*)yb1)[lane];
    float2 a11 = ((const float2*)(yb1 + 128))[lane];

    const int* esrc = edge + MM;

    for (int base = start; base < end; base += 64) {
        const int n = min(end - base, 64);
        int nout = 0; float w0 = 0.f, w1 = 0.f;
        if (lane < n) {
            const int m = bucket[base + lane];
            nout = esrc[m];
            w0   = Am[m];          // b = 0
            w1   = Am[MM + m];     // b = 1
        }
        int e = 0;
        for (; e + 2 <= n; e += 2) {
            const int   noA = __builtin_amdgcn_readlane(nout, e);
            const float wA0 = __uint_as_float(__builtin_amdgcn_readlane(__float_as_uint(w0), e));
            const float wA1 = __uint_as_float(__builtin_amdgcn_readlane(__float_as_uint(w1), e));
            const int   noB = __builtin_amdgcn_readlane(nout, e + 1);
            const float wB0 = __uint_as_float(__builtin_amdgcn_readlane(__float_as_uint(w0), e + 1));
            const float wB1 = __uint_as_float(__builtin_amdgcn_readlane(__float_as_uint(w1), e + 1));
            const float* pA0 = y + (size_t)noA * 256;
            const float* pA1 = y + (size_t)(TT + noA) * 256;
            const float* pB0 = y + (size_t)noB * 256;
            const float* pB1 = y + (size_t)(TT + noB) * 256;
            const float2 vA00 = ((const float2*)pA0)[lane];
            const float2 vA01 = ((const float2*)(pA0 + 128))[lane];
            const float2 vA10 = ((const float2*)pA1)[lane];
            const float2 vA11 = ((const float2*)(pA1 + 128))[lane];
            const float2 vB00 = ((const float2*)pB0)[lane];
            const float2 vB01 = ((const float2*)(pB0 + 128))[lane];
            const float2 vB10 = ((const float2*)pB1)[lane];
            const float2 vB11 = ((const float2*)(pB1 + 128))[lane];
            a00.x += wA0 * vA00.x; a00.y += wA0 * vA00.y;
            a01.x += wA0 * vA01.x; a01.y += wA0 * vA01.y;
            a10.x += wA1 * vA10.x; a10.y += wA1 * vA10.y;
            a11.x += wA1 * vA11.x; a11.y += wA1 * vA11.y;
            a00.x += wB0 * vB00.x; a00.y += wB0 * vB00.y;
            a01.x += wB0 * vB01.x; a01.y += wB0 * vB01.y;
            a10.x += wB1 * vB10.x; a10.y += wB1 * vB10.y;
            a11.x += wB1 * vB11.x; a11.y += wB1 * vB11.y;
        }
        if (e < n) {
            const int   no  = __builtin_amdgcn_readlane(nout, e);
            const float ww0 = __uint_as_float(__builtin_amdgcn_readlane(__float_as_uint(w0), e));
            const float ww1 = __uint_as_float(__builtin_amdgcn_readlane(__float_as_uint(w1), e));
            const float* p0 = y + (size_t)no * 256;
            const float* p1 = y + (size_t)(TT + no) * 256;
            const float2 v00 = ((const float2*)p0)[lane];
            const float2 v01 = ((const float2*)(p0 + 128))[lane];
            const float2 v10 = ((const float2*)p1)[lane];
            const float2 v11 = ((const float2*)(p1 + 128))[lane];
            a00.x += ww0 * v00.x; a00.y += ww0 * v00.y;
            a01.x += ww0 * v01.x; a01.y += ww0 * v01.y;
            a10.x += ww1 * v10.x; a10.y += ww1 * v10.y;
            a11.x += ww1 * v11.x; a11.y += ww1 * v11.y;
        }
    }

    const float2 bs = ((const float2*)bias)[lane];
    float* o0 = out + (size_t)t * 256;
    float* o1 = out + (size_t)(TT + t) * 256;
    float2 r;
    r.x = a00.x + bs.x; r.y = a00.y + bs.y; ((float2*)o0)[lane]         = r;
    r.x = a01.x + bs.x; r.y = a01.y + bs.y; ((float2*)(o0 + 128))[lane] = r;
    r.x = a10.x + bs.x; r.y = a10.y + bs.y; ((float2*)o1)[lane]         = r;
    r.x = a11.x + bs.x; r.y = a11.y + bs.y; ((float2*)(o1 + 128))[lane] = r;
}

// ---------------------------------------------------------------------------
extern "C" void kernel_launch(void* const* d_in, const int* in_sizes, int n_in,
                              void* d_out, int out_size, void* d_ws, size_t ws_size,
                              hipStream_t stream) {
    const float* x1   = (const float*)d_in[0];   // (B,T,2,D)
    // d_in[1] = x_2nd, unused by the reference
    const int*   edge = (const int*)d_in[2];     // (2,M)
    const float* Am   = (const float*)d_in[3];   // (B,1,M)
    const float* W    = (const float*)d_in[4];   // (DOUT,D)
    const float* bias = (const float*)d_in[5];   // (DOUT,)
    float* out = (float*)d_out;                  // (B,T,2,DOUT)

    // Workspace layout
    float* y      = (float*)d_ws;                          // NROWS*128 fp32 = 20.48 MB
    int*   cur    = (int*)d_ws + (size_t)NROWS * DOUTN;    // TT ints
    int*   bar    = cur + TT;                              // 8 ints (grid-barrier counters)
    int*   bucket = bar + 8;                               // MM ints

    hipMemsetAsync(cur, 0, (TT + 8) * sizeof(int), stream);   // zeroes cur + barrier counters
    csr_kernel<<<CSR_NB, 256, 0, stream>>>(edge, cur, bucket, bar);
    gemm_y_kernel<<<NTILES / 4, 256, 0, stream>>>(x1, W, y);
    gather_kernel<<<TT / 4, 256, 0, stream>>>(y, edge, Am, cur, bucket, bias, out);
}

// Round 2
// 527.310 us; speedup vs baseline: 1.3266x; 1.3266x over previous
//
#include <hip/hip_runtime.h>
#include <hip/hip_bf16.h>

// Problem constants (from reference): B,T,M,D,DOUT = 2,10000,100000,128,128
#define BB    2
#define TT    10000
#define MM    100000
#define DD    128
#define DOUTN 128
#define NROWS (BB * TT * 2)     // 40000 rows of X / y / out
#define NTILES (NROWS / 16)     // 2500 MFMA row-tiles (exact)
#define WPITCH 136              // LDS pitch in shorts: 272 B/row -> 2-way-only bank aliasing

typedef float  f32x4  __attribute__((ext_vector_type(4)));
typedef short  bf16x8 __attribute__((ext_vector_type(8)));

static __device__ __forceinline__ short f2bf(float f) {
    union { float f; unsigned u; } v; v.f = f;
    unsigned r = v.u + 0x7fffu + ((v.u >> 16) & 1u);   // RNE
    return (short)(r >> 16);
}

// ---------------------------------------------------------------------------
// GEMM: y = X * W^T (no bias). Block stages W->bf16 in LDS once; each wave
// computes one 16-row x 128-col tile. 625 blocks x 4 waves = 2500 tiles exact.
// ---------------------------------------------------------------------------
__global__ __launch_bounds__(256)
void gemm_y_kernel(const float* __restrict__ X, const float* __restrict__ W,
                   float* __restrict__ y) {
    __shared__ __align__(16) short Wb[DOUTN * WPITCH];   // 34.8 KB

    const int tid = threadIdx.x;
    {
        const int n  = tid >> 1;            // output col 0..127
        const int kh = (tid & 1) * 64;      // k half
        const float* wp = W + n * DD + kh;
        short* dst = &Wb[n * WPITCH + kh];
#pragma unroll
        for (int e = 0; e < 8; ++e) {
            float4 a = *(const float4*)(wp + e * 8);
            float4 b = *(const float4*)(wp + e * 8 + 4);
            bf16x8 t;
            t[0] = f2bf(a.x); t[1] = f2bf(a.y); t[2] = f2bf(a.z); t[3] = f2bf(a.w);
            t[4] = f2bf(b.x); t[5] = f2bf(b.y); t[6] = f2bf(b.z); t[7] = f2bf(b.w);
            *(bf16x8*)(dst + e * 8) = t;
        }
    }
    __syncthreads();

    const int lane = tid & 63;
    const int wid  = tid >> 6;
    const int l15  = lane & 15;
    const int q    = lane >> 4;             // 0..3
    const int tile = blockIdx.x * 4 + wid;  // 0..2499, always valid

    bf16x8 bfrag[8][4];
#pragma unroll
    for (int ot = 0; ot < 8; ++ot)
#pragma unroll
        for (int s = 0; s < 4; ++s)
            bfrag[ot][s] = *(const bf16x8*)&Wb[(ot * 16 + l15) * WPITCH + s * 32 + q * 8];

    const float* xp = X + (size_t)(tile * 16 + l15) * DD + q * 8;
    bf16x8 afrag[4];
#pragma unroll
    for (int s = 0; s < 4; ++s) {
        float4 a0 = *(const float4*)(xp + s * 32);
        float4 a1 = *(const float4*)(xp + s * 32 + 4);
        bf16x8 t;
        t[0] = f2bf(a0.x); t[1] = f2bf(a0.y); t[2] = f2bf(a0.z); t[3] = f2bf(a0.w);
        t[4] = f2bf(a1.x); t[5] = f2bf(a1.y); t[6] = f2bf(a1.z); t[7] = f2bf(a1.w);
        afrag[s] = t;
    }

    f32x4 acc[8];
#pragma unroll
    for (int ot = 0; ot < 8; ++ot) acc[ot] = (f32x4){0.f, 0.f, 0.f, 0.f};
#pragma unroll
    for (int s = 0; s < 4; ++s)
#pragma unroll
        for (int ot = 0; ot < 8; ++ot)
            acc[ot] = __builtin_amdgcn_mfma_f32_16x16x32_bf16(afrag[s], bfrag[ot][s], acc[ot], 0, 0, 0);

#pragma unroll
    for (int ot = 0; ot < 8; ++ot) {
        const int col = ot * 16 + l15;
#pragma unroll
        for (int r = 0; r < 4; ++r) {
            const int row = tile * 16 + q * 4 + r;
            y[(size_t)row * DOUTN + col] = acc[ot][r];
        }
    }
}

// ---------------------------------------------------------------------------
// CSR build: cnt -> scan -> fill. Three tiny launches (~1 us each) — measured
// cheaper than any fused grid-barrier variant (device-scope fences cost ~85 us
// per barrier on 8-XCD CDNA4; see round-1 post-mortem).
// ---------------------------------------------------------------------------
__global__ __launch_bounds__(256)
void hist_kernel(const int* __restrict__ edge, int* __restrict__ cnt) {
    const int m = blockIdx.x * 256 + threadIdx.x;
    if (m < MM) atomicAdd(&cnt[edge[m]], 1);   // edge[0][m] = node_in = dest
}

#define SCAN_T 1024
#define SCAN_CH 10    // 1024*10 = 10240 >= TT
__global__ __launch_bounds__(SCAN_T)
void scan_kernel(int* __restrict__ cur) {
    __shared__ int sh[SCAN_T];
    const int tid = threadIdx.x;
    int vals[SCAN_CH];
    int sum = 0;
    const int base_i = tid * SCAN_CH;
#pragma unroll
    for (int j = 0; j < SCAN_CH; ++j) {
        const int i = base_i + j;
        const int v = (i < TT) ? cur[i] : 0;
        vals[j] = v; sum += v;
    }
    sh[tid] = sum;
    __syncthreads();
    for (int off = 1; off < SCAN_T; off <<= 1) {
        const int v = (tid >= off) ? sh[tid - off] : 0;
        __syncthreads();
        sh[tid] += v;
        __syncthreads();
    }
    int run = (tid == 0) ? 0 : sh[tid - 1];
#pragma unroll
    for (int j = 0; j < SCAN_CH; ++j) {
        const int i = base_i + j;
        if (i < TT) { cur[i] = run; run += vals[j]; }
    }
}

__global__ __launch_bounds__(256)
void fill_kernel(const int* __restrict__ edge, int* __restrict__ cur,
                 int* __restrict__ bucket) {
    const int m = blockIdx.x * 256 + threadIdx.x;
    if (m < MM) {
        const int p = atomicAdd(&cur[edge[m]], 1);
        bucket[p] = m;
    }
    // after this kernel: cur[t] == end of bucket t (inclusive prefix)
}

// ---------------------------------------------------------------------------
// Gather: one WAVE per node t handles all 4 (b,c) output rows.
//   out[(b,t,c),:] = y[(b,t,c),:] + bias + sum_{m: in_m=t} Am[b,m]*y[(b,out_m,c),:]
// Bucket metadata loaded lane-parallel, broadcast via readlane. Edge loop
// unrolled x2: 8 independent row-loads in flight per wait instead of 4.
// ---------------------------------------------------------------------------
__global__ __launch_bounds__(256)
void gather_kernel(const float* __restrict__ y, const int* __restrict__ edge,
                   const float* __restrict__ Am, const int* __restrict__ cur_end,
                   const int* __restrict__ bucket, const float* __restrict__ bias,
                   float* __restrict__ out) {
    const int lane = threadIdx.x & 63;
    const int t    = blockIdx.x * 4 + (threadIdx.x >> 6);   // 2500*4 = 10000 exact

    const int end   = cur_end[t];
    const int start = (t == 0) ? 0 : cur_end[t - 1];

    // accumulators: a[b][c] as float2 per lane; init with own row of y
    const float* yb0 = y + (size_t)t * 256;            // (b0,t,c0) row; c1 at +128
    const float* yb1 = y + (size_t)(TT + t) * 256;     // (b1,t,c0) row; c1 at +128
    float2 a00 = ((const float2*)yb0)[lane];
    float2 a01 = ((const float2*)(yb0 + 128))[lane];
    float2 a10 = ((const float2*)yb1)[lane];
    float2 a11 = ((const float2*)(yb1 + 128))[lane];

    const int* esrc = edge + MM;

    for (int base = start; base < end; base += 64) {
        const int n = min(end - base, 64);
        int nout = 0; float w0 = 0.f, w1 = 0.f;
        if (lane < n) {
            const int m = bucket[base + lane];
            nout = esrc[m];
            w0   = Am[m];          // b = 0
            w1   = Am[MM + m];     // b = 1
        }
        int e = 0;
        for (; e + 2 <= n; e += 2) {
            const int   noA = __builtin_amdgcn_readlane(nout, e);
            const float wA0 = __uint_as_float(__builtin_amdgcn_readlane(__float_as_uint(w0), e));
            const float wA1 = __uint_as_float(__builtin_amdgcn_readlane(__float_as_uint(w1), e));
            const int   noB = __builtin_amdgcn_readlane(nout, e + 1);
            const float wB0 = __uint_as_float(__builtin_amdgcn_readlane(__float_as_uint(w0), e + 1));
            const float wB1 = __uint_as_float(__builtin_amdgcn_readlane(__float_as_uint(w1), e + 1));
            const float* pA0 = y + (size_t)noA * 256;
            const float* pA1 = y + (size_t)(TT + noA) * 256;
            const float* pB0 = y + (size_t)noB * 256;
            const float* pB1 = y + (size_t)(TT + noB) * 256;
            const float2 vA00 = ((const float2*)pA0)[lane];
            const float2 vA01 = ((const float2*)(pA0 + 128))[lane];
            const float2 vA10 = ((const float2*)pA1)[lane];
            const float2 vA11 = ((const float2*)(pA1 + 128))[lane];
            const float2 vB00 = ((const float2*)pB0)[lane];
            const float2 vB01 = ((const float2*)(pB0 + 128))[lane];
            const float2 vB10 = ((const float2*)pB1)[lane];
            const float2 vB11 = ((const float2*)(pB1 + 128))[lane];
            a00.x += wA0 * vA00.x; a00.y += wA0 * vA00.y;
            a01.x += wA0 * vA01.x; a01.y += wA0 * vA01.y;
            a10.x += wA1 * vA10.x; a10.y += wA1 * vA10.y;
            a11.x += wA1 * vA11.x; a11.y += wA1 * vA11.y;
            a00.x += wB0 * vB00.x; a00.y += wB0 * vB00.y;
            a01.x += wB0 * vB01.x; a01.y += wB0 * vB01.y;
            a10.x += wB1 * vB10.x; a10.y += wB1 * vB10.y;
            a11.x += wB1 * vB11.x; a11.y += wB1 * vB11.y;
        }
        if (e < n) {
            const int   no  = __builtin_amdgcn_readlane(nout, e);
            const float ww0 = __uint_as_float(__builtin_amdgcn_readlane(__float_as_uint(w0), e));
            const float ww1 = __uint_as_float(__builtin_amdgcn_readlane(__float_as_uint(w1), e));
            const float* p0 = y + (size_t)no * 256;
            const float* p1 = y + (size_t)(TT + no) * 256;
            const float2 v00 = ((const float2*)p0)[lane];
            const float2 v01 = ((const float2*)(p0 + 128))[lane];
            const float2 v10 = ((const float2*)p1)[lane];
            const float2 v11 = ((const float2*)(p1 + 128))[lane];
            a00.x += ww0 * v00.x; a00.y += ww0 * v00.y;
            a01.x += ww0 * v01.x; a01.y += ww0 * v01.y;
            a10.x += ww1 * v10.x; a10.y += ww1 * v10.y;
            a11.x += ww1 * v11.x; a11.y += ww1 * v11.y;
        }
    }

    const float2 bs = ((const float2*)bias)[lane];
    float* o0 = out + (size_t)t * 256;
    float* o1 = out + (size_t)(TT + t) * 256;
    float2 r;
    r.x = a00.x + bs.x; r.y = a00.y + bs.y; ((float2*)o0)[lane]         = r;
    r.x = a01.x + bs.x; r.y = a01.y + bs.y; ((float2*)(o0 + 128))[lane] = r;
    r.x = a10.x + bs.x; r.y = a10.y + bs.y; ((float2*)o1)[lane]         = r;
    r.x = a11.x + bs.x; r.y = a11.y + bs.y; ((float2*)(o1 + 128))[lane] = r;
}

// ---------------------------------------------------------------------------
extern "C" void kernel_launch(void* const* d_in, const int* in_sizes, int n_in,
                              void* d_out, int out_size, void* d_ws, size_t ws_size,
                              hipStream_t stream) {
    const float* x1   = (const float*)d_in[0];   // (B,T,2,D)
    // d_in[1] = x_2nd, unused by the reference
    const int*   edge = (const int*)d_in[2];     // (2,M)
    const float* Am   = (const float*)d_in[3];   // (B,1,M)
    const float* W    = (const float*)d_in[4];   // (DOUT,D)
    const float* bias = (const float*)d_in[5];   // (DOUT,)
    float* out = (float*)d_out;                  // (B,T,2,DOUT)

    // Workspace layout
    float* y      = (float*)d_ws;                          // NROWS*128 fp32 = 20.48 MB
    int*   cur    = (int*)d_ws + (size_t)NROWS * DOUTN;    // TT ints
    int*   bucket = cur + TT;                              // MM ints

    hipMemsetAsync(cur, 0, TT * sizeof(int), stream);
    hist_kernel<<<(MM + 255) / 256, 256, 0, stream>>>(edge, cur);
    scan_kernel<<<1, SCAN_T, 0, stream>>>(cur);
    fill_kernel<<<(MM + 255) / 256, 256, 0, stream>>>(edge, cur, bucket);

    gemm_y_kernel<<<NTILES / 4, 256, 0, stream>>>(x1, W, y);

    gather_kernel<<<TT / 4, 256, 0, stream>>>(y, edge, Am, cur, bucket, bias, out);
}